// Round 15
// baseline (511.806 us; speedup 1.0000x reference)
//
#include <hip/hip_runtime.h>

#define MAX_ITER 8192
#define NCHUNK   64
#define NCHUNKS  128          // MAX_ITER / NCHUNK
#define NSCAN    64           // scanner blocks, 1 sample each
#define NTHREADS 512
#define NWAVES   8
#define TPW      8            // t's per wave in scan/fold phases

typedef unsigned long long u64;
#define KEY_MAX  0xffffffffffffffffull
#define POISON64 0xAAAAAAAAAAAAAAAAull   // d_ws re-poison pattern (0xAA bytes)

// IEEE fp32 ops, contraction off -> bitwise numpy match (verified many rounds).
__device__ __forceinline__ float mul_rn(float a, float b) {
#pragma clang fp contract(off)
  return a * b;
}
__device__ __forceinline__ float add_rn(float a, float b) {
#pragma clang fp contract(off)
  return a + b;
}
__device__ __forceinline__ float sub_rn(float a, float b) {
#pragma clang fp contract(off)
  return a - b;
}
__device__ __forceinline__ float dist2_rn(float px, float py, float sx, float sy) {
  const float dx = sub_rn(px, sx), dy = sub_rn(py, sy);
  return add_rn(mul_rn(dx, dx), mul_rn(dy, dy));
}
__device__ __forceinline__ float bcastf(float v, int lane) {
  return __int_as_float(__builtin_amdgcn_readlane(__float_as_int(v), lane));
}
__device__ __forceinline__ float bpermf(int srcByte, float v) {
  return __int_as_float(__builtin_amdgcn_ds_bpermute(srcByte, __float_as_int(v)));
}
__device__ __forceinline__ void st_agent(u64* p, u64 v) {
  __hip_atomic_store(p, v, __ATOMIC_RELAXED, __HIP_MEMORY_SCOPE_AGENT);
}
__device__ __forceinline__ u64 ld_agent(u64* p) {
  return __hip_atomic_load(p, __ATOMIC_RELAXED, __HIP_MEMORY_SCOPE_AGENT);
}
__device__ __forceinline__ u64 packf2(float x, float y) {
  return ((u64)__float_as_uint(y) << 32) | (u64)__float_as_uint(x);
}
__device__ __forceinline__ float lo32f(u64 v) {
  return __uint_as_float((unsigned)(v & 0xffffffffu));
}
__device__ __forceinline__ float hi32f(u64 v) {
  return __uint_as_float((unsigned)(v >> 32));
}
__device__ __forceinline__ void compiler_fence() {
  asm volatile("" ::: "memory");
}
// LDS-only barrier (r14): all cross-wave communication is LDS; global
// visibility to other blocks is poison/tag-gated at the consumer.
__device__ __forceinline__ void barrier_lds() {
  asm volatile("s_waitcnt lgkmcnt(0)\n\ts_barrier" ::: "memory");
}
// Exact (d2, idx) lex key: d2>=0 -> bit-monotone; ties -> lowest idx.
// Published u64s carry a tag in bits 13..20 (value+128, range 130..255);
// idx occupies bits 0..12 (< 8192) so tag bits are clean.  0xAA poison ->
// tag 85, initial zeros -> tag 0: neither can false-match.
__device__ __forceinline__ u64 mkkey(float d2, int idx) {
  return ((u64)__float_as_uint(d2) << 32) | (u64)(unsigned)idx;
}
__device__ __forceinline__ unsigned tagof(u64 kv) {
  return ((unsigned)(kv >> 13)) & 0xFFu;
}
__device__ __forceinline__ void load_sample(const float* __restrict__ u,
                                            const float* __restrict__ r,
                                            float gx, float gy, int idx,
                                            float& ox, float& oy) {
  const float uu = u[idx];
  if (uu < 0.1f) { ox = gx; oy = gy; }
  else { ox = mul_rn(r[2 * idx], 200.0f); oy = mul_rn(r[2 * idx + 1], 200.0f); }
}

__global__ __launch_bounds__(NTHREADS) void rrt_kernel(
    const float* __restrict__ state, const float* __restrict__ goal,
    const float* __restrict__ u, const float* __restrict__ r,
    float* __restrict__ out, unsigned* __restrict__ ws) {
  // LDS union: scanner blocks stage nodes; block 0 coordinator scratch.
  __shared__ __align__(16) union {
    struct { float2 nodes[7936]; u64 K[NWAVES]; } s;               // 63552 B
    struct { u64 qtmp[64]; u64 qfin[64]; u64 mask[NWAVES];
             u64 fkS[NWAVES][64]; u64 fkT[4][64]; float bd2f[64]; } c;
  } sh;

  u64* outU  = (u64*)out;               // node i at outU[i] (float2-packed)
  // LAG-4 rings (4 slots x 64), all entries independently tagged (tag
  // j+128 for the consuming merge j): MbufK = (d2|tag|idx) key; MbufX/Y =
  // winner coords (float in high 32b | tag).  Order-free validation: the
  // coordinator requires ALL THREE tags to match -> no C-before-K race.
  // Scanner iter i writes slot i&3 with tag i+132 (consumed at j=i+4).
  // Slot reuse (iter i+4) gated on Nb chunk i+4, published only after
  // merge j=i+4 consumed iter i's M.
  u64* MbufK = (u64*)(ws + 64);         // bytes  256..2303
  u64* MbufX = (u64*)(ws + 576);        // bytes 2304..4351
  u64* MbufY = (u64*)(ws + 1088);       // bytes 4352..6399
  u64* Nb    = (u64*)(ws + 1600);       // bytes 6400..71935
  // Nb[m] = node m+1, written ONCE; 0xAA poison is an impossible node value
  // (all nodes >= 0; 0xAAAAAAAA is negative).  Data IS the ready flag.

  const int tid  = threadIdx.x;
  const int wave = tid >> 6;
  const int lane = tid & 63;
  const int blk  = blockIdx.x;

  const float n0x = state[0], n0y = state[1];
  const float gx = goal[0],  gy = goal[1];

  if (blk == 0) {
    // ======== coordinator team: 8 waves, TWO barriers per chunk ============
    // Per chunk: A (w0: merge+repair+steer) | b1 | B (all: scan + spec-fold
    // chunk j + final-folds chunk j-1) | b2 | C (w0: pops + publish) -> A.
    if (tid < 256) ((u64*)sh.c.fkT)[tid] = KEY_MAX;   // init fold ring
    if (tid == 0) st_agent(&outU[0], packf2(n0x, n0y));   // node 0
    barrier_lds();

    // all waves hold rolling samples: s=chunk j, s1=j+1, s2=j+2
    float sx, sy, s1x, s1y, s2x, s2y;
    load_sample(u, r, gx, gy, lane, sx, sy);
    load_sample(u, r, gx, gy, NCHUNK + lane, s1x, s1y);
    load_sample(u, r, gx, gy, 2 * NCHUNK + lane, s2x, s2y);

    // wave-0 state: q history (nx=q_{j-1} at A_j, pnx=q_{j-2}, ppnx=q_{j-3});
    // chg = lanes whose q changed during last chunk's pops (repair set);
    // M triples: P1 consumed at next A, P2 one chunk behind.
    float nx = 0.0f, ny = 0.0f, pnx = 0.0f, pny = 0.0f, ppnx = 0.0f, ppny = 0.0f;
    u64 chg = 0;
    u64 kvP1 = 0, xvP1 = 0, yvP1 = 0, kvP2 = 0, xvP2 = 0, yvP2 = 0;

    for (int j = 0; j < NCHUNKS; ++j) {
      const int c = j * NCHUNK;

      // all waves: prefetch chunk j+3 sample (rotates into s2)
      float s3x = 0.0f, s3y = 0.0f;
      if (j + 3 < NCHUNKS)
        load_sample(u, r, gx, gy, (j + 3) * NCHUNK + lane, s3x, s3y);

      float bd2 = 0.0f;

      // ---- Phase A (wave 0): carry assembly + M merge + steer + share ----
      if (wave == 0) {
        // carry part 1: chunk j-1 spec partials (from B_{j-1}), repaired.
        // chg is wave-uniform (ballot).  Clean wave-partials used stale q
        // only where q didn't change -> bit-identical; dirty partials
        // recomputed from FINAL q_{j-1} (= nx,ny).  Keys: order-free min.
        u64 carK = KEY_MAX;
        if (j >= 1) {
          const int base = c - NCHUNK;
          #pragma unroll
          for (int w = 0; w < NWAVES; ++w) {
            u64 pw;
            if ((chg >> (w * TPW)) & 0xFFull) {
              pw = KEY_MAX;
              #pragma unroll
              for (int tt = 0; tt < TPW; ++tt) {
                const int t = w * TPW + tt;
                const float px = bcastf(nx, t), py = bcastf(ny, t);
                const u64 k = mkkey(dist2_rn(px, py, sx, sy), base + t + 1);
                if (k < pw) pw = k;
              }
            } else {
              pw = sh.c.fkS[w][lane];
            }
            if (pw < carK) carK = pw;
          }
        }
        // carry part 2: chunks j-2, j-3 (final-folds accumulated in fkT)
        {
          const u64 ft = sh.c.fkT[j & 3][lane];
          sh.c.fkT[j & 3][lane] = KEY_MAX;    // clear for target j+4
          if (ft < carK) carK = ft;
        }

        // M: key + coords come directly from the scanner triple.
        u64 Mkey; float mxx = n0x, myy = n0y;
        if (j >= 4) {
          const unsigned want = (unsigned)(j + 128);
          if (!__all((int)((tagof(kvP1) == want) & (tagof(xvP1) == want) &
                           (tagof(yvP1) == want)))) {
            const unsigned sl = ((unsigned)(j - 4)) & 3u;
            for (;;) {      // rare fallback: poll all three
              kvP1 = ld_agent(&MbufK[sl * 64 + lane]);
              xvP1 = ld_agent(&MbufX[sl * 64 + lane]);
              yvP1 = ld_agent(&MbufY[sl * 64 + lane]);
              if (__all((int)((tagof(kvP1) == want) & (tagof(xvP1) == want) &
                              (tagof(yvP1) == want)))) break;
              __builtin_amdgcn_s_sleep(1);
            }
            compiler_fence();
          }
          Mkey = (kvP1 & 0xFFFFFFFF00000000ull) | (u64)((unsigned)kvP1 & 0x1FFFu);
          mxx = hi32f(xvP1); myy = hi32f(yvP1);
        } else {
          Mkey = mkkey(dist2_rn(n0x, n0y, sx, sy), 0);
        }

        // carry-winner coords from q-history registers via bpermute
        // (garbage when carK==KEY_MAX -> discarded by cWin=false).
        const unsigned ci = (unsigned)carK & 0x1FFFu;
        const int srcB = (((int)ci - 1) & 63) * 4;
        const int ch = ((int)ci - 1) >> 6;        // winner's chunk
        const float a0x = bpermf(srcB, nx),   a0y = bpermf(srcB, ny);
        const float a1x = bpermf(srcB, pnx),  a1y = bpermf(srcB, pny);
        const float a2x = bpermf(srcB, ppnx), a2y = bpermf(srcB, ppny);
        const float cx = (ch == j - 1) ? a0x : ((ch == j - 2) ? a1x : a2x);
        const float cy = (ch == j - 1) ? a0y : ((ch == j - 2) ? a1y : a2y);

        // merge: M range strictly below carry range -> u64 key-min exact.
        const bool cWin = (carK < Mkey);
        const u64 winK = cWin ? carK : Mkey;
        bd2 = hi32f(winK);
        const float wbx = cWin ? cx : mxx;
        const float wby = cWin ? cy : myy;

        // q-history shift, then steer (verified math)
        ppnx = pnx; ppny = pny; pnx = nx; pny = ny;
        const float dirx = sub_rn(sx, wbx), diry = sub_rn(sy, wby);
        const float dist = __fsqrt_rn(add_rn(bd2, 1e-12f));
        const float scl = (dist > 5.0f) ? __fdiv_rn(5.0f, dist) : 1.0f;
        nx = add_rn(wbx, mul_rn(dirx, scl));
        ny = add_rn(wby, mul_rn(diry, scl));
        sh.c.qtmp[lane] = packf2(nx, ny);   // pre-pop q_j
        sh.c.bd2f[lane] = bd2;              // post-merge bd2
      }
      barrier_lds();                        // b1: (q, bd2) shared

      // ---- Phase B (all waves): scan + spec-fold (chunk j, pre-pop q) +
      //      final-folds (chunk j-1, final q from qfin) -- 8 t's per wave.
      {
        float qxl, qyl, bb;
        if (wave == 0) { qxl = nx; qyl = ny; bb = bd2; }
        else {
          const u64 qv = sh.c.qtmp[lane];
          qxl = lo32f(qv); qyl = hi32f(qv);
          bb = sh.c.bd2f[lane];
        }
        float pfx = 0.0f, pfy = 0.0f;
        if (j >= 1) {
          const u64 qv = sh.c.qfin[lane];
          pfx = lo32f(qv); pfy = hi32f(qv);
        }
        unsigned mw = 0;
        u64 kS = KEY_MAX, kT1 = KEY_MAX, kT2 = KEY_MAX;
        const int t0 = wave * TPW;
        #pragma unroll
        for (int tt = 0; tt < TPW; ++tt) {
          const int t = t0 + tt;
          const float px = bcastf(qxl, t), py = bcastf(qyl, t);
          // scan (r9-exact: pre-pop q, post-merge bd2)
          const float d = dist2_rn(px, py, sx, sy);
          const u64 bal = __ballot(d < bb);
          if (t < 63 && (bal >> (t + 1)) != 0ull) mw |= (1u << tt);
          // spec-fold chunk j vs s_{j+1} (repaired at A_{j+1})
          const u64 ks = mkkey(dist2_rn(px, py, s1x, s1y), c + t + 1);
          if (ks < kS) kS = ks;
          // final-folds chunk j-1 vs s_{j+1}, s_{j+2}
          if (j >= 1) {
            const float fx = bcastf(pfx, t), fy = bcastf(pfy, t);
            const int fidx = c - NCHUNK + t + 1;
            const u64 k1 = mkkey(dist2_rn(fx, fy, s1x, s1y), fidx);
            if (k1 < kT1) kT1 = k1;
            const u64 k2 = mkkey(dist2_rn(fx, fy, s2x, s2y), fidx);
            if (k2 < kT2) kT2 = k2;
          }
        }
        sh.c.mask[wave] = ((u64)mw) << t0;
        sh.c.fkS[wave][lane] = kS;
        if (j >= 1) {
          atomicMin(&sh.c.fkT[(j + 1) & 3][lane], kT1);
          atomicMin(&sh.c.fkT[(j + 2) & 3][lane], kT2);
        }
      }
      barrier_lds();                        // b2: masks + folds ready

      // ---- Phase C (wave 0): pops (r9-exact) + publish + preloads ----
      if (wave == 0) {
        u64 cand = 0;
        #pragma unroll
        for (int w = 0; w < NWAVES; ++w) cand |= sh.c.mask[w];
        // M-triple pipeline: promote P2 (loaded C_{j-1}, for merge j+1);
        // load P2 for merge j+2 (slot (j-2)&3, tag j+130).
        kvP1 = kvP2; xvP1 = xvP2; yvP1 = yvP2;
        if (j >= 2 && j + 2 < NCHUNKS) {
          const unsigned sl = ((unsigned)(j - 2)) & 3u;
          kvP2 = ld_agent(&MbufK[sl * 64 + lane]);
          xvP2 = ld_agent(&MbufX[sl * 64 + lane]);
          yvP2 = ld_agent(&MbufY[sl * 64 + lane]);
        }
        u64 chgNew = 0;
        while (cand) {
          const int t = (int)__builtin_ctzll(cand);
          cand &= (cand - 1);
          const float px = bcastf(nx, t);
          const float py = bcastf(ny, t);
          const float d = dist2_rn(px, py, sx, sy);
          const bool upd = (lane > t) && (d < bd2);
          const u64 ub = __ballot(upd);
          if (ub != 0ull) {
            if (upd) {                  // exact sequential update body
              bd2 = d;
              const float dirx = sub_rn(sx, px), diry = sub_rn(sy, py);
              const float dist = __fsqrt_rn(add_rn(d, 1e-12f));
              const float scl = (dist > 5.0f) ? __fdiv_rn(5.0f, dist) : 1.0f;
              nx = add_rn(px, mul_rn(dirx, scl));
              ny = add_rn(py, mul_rn(diry, scl));
            }
            chgNew |= ub;               // these lanes' q changed
            cand |= ub;                 // their steps become candidates
          }
        }
        chg = chgNew;
        const u64 pv = packf2(nx, ny);
        st_agent(&outU[c + lane + 1], pv);
        st_agent(&Nb[c + lane], pv);
        sh.c.qfin[lane] = pv;           // final q_j for B_{j+1} folds
      }
      // no barrier here: helpers wait at b1_{j+1}; wave0's qfin write is
      // ordered by its own lgkmcnt(0) at b1_{j+1}.

      // all waves: rotate samples
      sx = s1x; sy = s1y; s1x = s2x; s1y = s2y; s2x = s3x; s2y = s3y;
    }
  } else {
    // ================= scanners: blocks 1..64, one sample each =============
    // LAG-4 (r14 verbatim + coords publication): iter i (0..123): issue Nb
    // load for chunk i; bulk-scan [1..64i] from LDS + node 0 under it;
    // wave-0 tail validates fresh chunk i via the poison gate, stages +
    // folds, publishes tagged {key, x, y} into ring slot i&3 (tag i+132,
    // for merge j=i+4 vs chunk (i+4)'s sample).
    const int b = blk - 1;

    for (int i = 0; i < NCHUNKS - 4; ++i) {
      const int c = i * NCHUNK;

      u64 nv = POISON64;
      if (wave == 0) nv = ld_agent(&Nb[c + lane]);   // issue early, check late

      // my sample: chunk i+4, slot b
      float sx, sy;
      load_sample(u, r, gx, gy, (i + 4) * NCHUNK + b, sx, sy);

      // ---- bulk scan of staged nodes [1..64i] + node 0 ----
      u64 key = KEY_MAX;
      if (tid == 0) key = mkkey(dist2_rn(n0x, n0y, sx, sy), 0);
      // 512 lanes stride node pairs; float4 = nodes (jj, jj+1), jj odd
      for (int jj = 1 + 2 * tid; jj < c; jj += 2 * NTHREADS) {
        const float4 p = *(const float4*)&sh.s.nodes[jj - 1];
        const u64 ka = mkkey(dist2_rn(p.x, p.y, sx, sy), jj);
        const u64 kb = mkkey(dist2_rn(p.z, p.w, sx, sy), jj + 1);
        if (ka < key) key = ka;     // lower idx first: exact argmin ties
        if (kb < key) key = kb;
      }
      #pragma unroll
      for (int m = 32; m >= 1; m >>= 1) {
        const u64 ok = __shfl_xor(key, m, 64);
        if (ok < key) key = ok;
      }
      if (lane == 0) sh.s.K[wave] = key;
      barrier_lds();                    // barrier A: partials ready

      // ---- wave-0 tail: validate fresh chunk i, stage, fold, publish ----
      if (wave == 0) {
        u64 kk = (lane < NWAVES) ? sh.s.K[lane] : KEY_MAX;
        u64 ok = __shfl_xor(kk, 1, 64); if (ok < kk) kk = ok;
        ok = __shfl_xor(kk, 2, 64);     if (ok < kk) kk = ok;
        ok = __shfl_xor(kk, 4, 64);     if (ok < kk) kk = ok;

        while (!__all((int)(nv != POISON64))) {   // data arrival = signal
          __builtin_amdgcn_s_sleep(1);
          nv = ld_agent(&Nb[c + lane]);
        }
        compiler_fence();
        const float px = lo32f(nv), py = hi32f(nv);
        {
          float2 p; p.x = px; p.y = py;
          sh.s.nodes[c + lane] = p;       // stage chunk i for future bulks
          const u64 ki = mkkey(dist2_rn(px, py, sx, sy), c + lane + 1);
          if (ki < kk) kk = ki;           // (d2,idx) key: order-free ties
        }
        #pragma unroll
        for (int m = 32; m >= 1; m >>= 1) {
          const u64 o2 = __shfl_xor(kk, m, 64);
          if (o2 < kk) kk = o2;
        }
        // winner coords (kk uniform after butterfly): node 0, fresh-chunk
        // (register path via bcast -- avoids same-iter LDS RAW), or staged.
        const unsigned midx = (unsigned)kk & 0x1FFFu;
        float wx, wy;
        if (midx == 0u) { wx = n0x; wy = n0y; }
        else if ((int)midx > c) {
          wx = bcastf(px, (int)midx - 1 - c);
          wy = bcastf(py, (int)midx - 1 - c);
        } else {
          const float2 p = sh.s.nodes[midx - 1];
          wx = p.x; wy = p.y;
        }
        if (lane == 0) {
          const unsigned sl = ((unsigned)i) & 3u;
          const u64 tg = (u64)(unsigned)(i + 132) << 13;
          st_agent(&MbufK[sl * 64 + b], kk | tg);
          st_agent(&MbufX[sl * 64 + b], ((u64)__float_as_uint(wx) << 32) | tg);
          st_agent(&MbufY[sl * 64 + b], ((u64)__float_as_uint(wy) << 32) | tg);
        }
      }
      // barrier B: gates next iter's bulk reads of freshly staged nodes and
      // K reuse.  LDS-only ordering -> lgkm barrier.
      barrier_lds();
    }
  }
}

extern "C" void kernel_launch(void* const* d_in, const int* in_sizes, int n_in,
                              void* d_out, int out_size, void* d_ws, size_t ws_size,
                              hipStream_t stream) {
  const float* state = (const float*)d_in[0];
  const float* goal  = (const float*)d_in[1];
  const float* u     = (const float*)d_in[2];
  const float* r     = (const float*)d_in[3];
  float* out = (float*)d_out;
  unsigned* ws = (unsigned*)d_ws;
  (void)in_sizes; (void)n_in; (void)out_size; (void)ws_size;
  rrt_kernel<<<NSCAN + 1, NTHREADS, 0, stream>>>(state, goal, u, r, out, ws);
}

// Round 16
// 364.226 us; speedup vs baseline: 1.4052x; 1.4052x over previous
//
#include <hip/hip_runtime.h>

#define MAX_ITER 8192
#define NCHUNK   64
#define NCHUNKS  128          // MAX_ITER / NCHUNK
#define NSCAN    64           // scanner blocks, 1 sample each
#define NTHREADS 512
#define NWAVES   8
#define TPW      8            // t's per wave in scan/fold phases

typedef unsigned long long u64;
#define KEY_MAX  0xffffffffffffffffull
#define POISON64 0xAAAAAAAAAAAAAAAAull   // d_ws re-poison pattern (0xAA bytes)

// IEEE fp32 ops, contraction off -> bitwise numpy match (verified many rounds).
__device__ __forceinline__ float mul_rn(float a, float b) {
#pragma clang fp contract(off)
  return a * b;
}
__device__ __forceinline__ float add_rn(float a, float b) {
#pragma clang fp contract(off)
  return a + b;
}
__device__ __forceinline__ float sub_rn(float a, float b) {
#pragma clang fp contract(off)
  return a - b;
}
__device__ __forceinline__ float dist2_rn(float px, float py, float sx, float sy) {
  const float dx = sub_rn(px, sx), dy = sub_rn(py, sy);
  return add_rn(mul_rn(dx, dx), mul_rn(dy, dy));
}
__device__ __forceinline__ float bcastf(float v, int lane) {
  return __int_as_float(__builtin_amdgcn_readlane(__float_as_int(v), lane));
}
__device__ __forceinline__ void st_agent(u64* p, u64 v) {
  __hip_atomic_store(p, v, __ATOMIC_RELAXED, __HIP_MEMORY_SCOPE_AGENT);
}
__device__ __forceinline__ u64 ld_agent(u64* p) {
  return __hip_atomic_load(p, __ATOMIC_RELAXED, __HIP_MEMORY_SCOPE_AGENT);
}
__device__ __forceinline__ u64 packf2(float x, float y) {
  return ((u64)__float_as_uint(y) << 32) | (u64)__float_as_uint(x);
}
__device__ __forceinline__ float lo32f(u64 v) {
  return __uint_as_float((unsigned)(v & 0xffffffffu));
}
__device__ __forceinline__ float hi32f(u64 v) {
  return __uint_as_float((unsigned)(v >> 32));
}
__device__ __forceinline__ void compiler_fence() {
  asm volatile("" ::: "memory");
}
// Exact (d2, idx) lex key: d2>=0 -> bit-monotone; ties -> lowest idx.
// Scanner-published keys also carry a tag in bits 13..20 (131..255); the
// coordinator STRIPS the tag before key comparison.  0xAA poison -> tag 85,
// can never false-match.
__device__ __forceinline__ u64 mkkey(float d2, int idx) {
  return ((u64)__float_as_uint(d2) << 32) | (u64)(unsigned)idx;
}
__device__ __forceinline__ unsigned tagof(u64 kv) {
  return ((unsigned)(kv >> 13)) & 0xFFu;
}
__device__ __forceinline__ void load_sample(const float* __restrict__ u,
                                            const float* __restrict__ r,
                                            float gx, float gy, int idx,
                                            float& ox, float& oy) {
  const float uu = u[idx];
  if (uu < 0.1f) { ox = gx; oy = gy; }
  else { ox = mul_rn(r[2 * idx], 200.0f); oy = mul_rn(r[2 * idx + 1], 200.0f); }
}

__global__ __launch_bounds__(NTHREADS) void rrt_kernel(
    const float* __restrict__ state, const float* __restrict__ goal,
    const float* __restrict__ u, const float* __restrict__ r,
    float* __restrict__ out, unsigned* __restrict__ ws) {
  // LDS union: scanner blocks stage nodes; block 0 small coordinator scratch.
  __shared__ __align__(16) union {
    struct { float2 nodes[7936]; u64 K[NWAVES]; } s;               // 63552 B
    struct { u64 qtmp[64]; u64 mask[NWAVES]; u64 fk1[NWAVES][64];
             u64 fk2[NWAVES][64]; float bd2[64]; } c;
  } sh;

  u64* outU  = (u64*)out;               // node i at outU[i] (float2-packed)
  // MbufK: 4-slot ring of 64 tagged keys, LAG-3 (r10-verified protocol).
  // Scanner iter i writes slot i&3, tag i+131: M over [0..64(i+1)] vs chunk
  // (i+3)'s sample.  Coordinator merge j (>=3) reads slot (j-3)&3 requiring
  // tag == j+128 EXACTLY (tags are sample-specific).  Slot reuse (iter i+4)
  // gated on Nb chunk i+4, published only after merge j=i+3 consumed iter
  // i's M.
  u64* MbufK = (u64*)(ws + 64);         // bytes 256..2303
  u64* Nb    = (u64*)(ws + 576);        // bytes 2304..67839
  // Nb[m] = node m+1, written ONCE; 0xAA poison is an impossible node value
  // (all nodes >= 0; 0xAAAAAAAA is negative).  Data IS the ready flag ->
  // no nflag, no vmcnt drain, no init guard.  u64 stores don't tear.

  const int tid  = threadIdx.x;
  const int wave = tid >> 6;
  const int lane = tid & 63;
  const int blk  = blockIdx.x;

  const float n0x = state[0], n0y = state[1];
  const float gx = goal[0],  gy = goal[1];

  if (blk == 0) {
    // ============ coordinator team: 8 waves, 4 barriers per chunk ==========
    if (tid == 0) st_agent(&outU[0], packf2(n0x, n0y));   // node 0

    // ALL waves maintain the rolling samples (identical loads -> identical
    // values): s = chunk j, s1 = chunk j+1.
    float sx, sy, s1x, s1y;
    load_sample(u, r, gx, gy, lane, sx, sy);
    load_sample(u, r, gx, gy, NCHUNK + lane, s1x, s1y);
    // wave-0 carry keys.  Invariant at merge j: c1K = min-key over chunks
    // j-2, j-1 vs s_j; c2K = chunk j-1 vs s_{j+1}.  (d2,idx) keys: order-
    // free exact ties.
    u64 c1K = KEY_MAX, c2K = KEY_MAX;
    u64 kvPre = 0, wvM = 0, wvC1 = 0;
    bool preOK = false;

    for (int j = 0; j < NCHUNKS; ++j) {
      const int c = j * NCHUNK;

      // all waves: prefetch chunk j+2 sample (becomes s1 next iter)
      float s2x = 0.0f, s2y = 0.0f;
      if (j + 2 < NCHUNKS)
        load_sample(u, r, gx, gy, (j + 2) * NCHUNK + lane, s2x, s2y);

      float bd2 = 0.0f, bx = 0.0f, by = 0.0f, nx = 0.0f, ny = 0.0f;

      // ---- Phase A (wave 0): merge + steer + share ----
      if (wave == 0) {
        u64 Mkey; float mx = n0x, my = n0y;
        if (j >= 3) {
          const unsigned want = (unsigned)(j + 128);
          u64 kv;
          if (preOK) {
            kv = kvPre;                 // gather wvM already in flight
          } else {                      // rare fallback: poll + dep. gather
            u64* slot = MbufK + (((unsigned)(j - 3)) & 3u) * 64;
            for (;;) {
              kv = ld_agent(&slot[lane]);
              if (__all((int)(tagof(kv) == want))) break;
              __builtin_amdgcn_s_sleep(1);
            }
            compiler_fence();
            const unsigned im = (unsigned)kv & 0x1FFFu;
            wvM = ld_agent(&Nb[(im ? im : 1u) - 1u]);
          }
          const unsigned midx = (unsigned)kv & 0x1FFFu;
          Mkey = (kv & 0xFFFFFFFF00000000ull) | (u64)midx;   // strip tag
          if (midx) { mx = lo32f(wvM); my = hi32f(wvM); }
        } else {
          Mkey = mkkey(dist2_rn(n0x, n0y, sx, sy), 0);
        }
        // merge: index ranges disjoint (M idx <= 64(j-2) < carry idx) ->
        // plain u64 key-min is the exact lex argmin incl. tie-breaks.
        const float cx = lo32f(wvC1), cy = hi32f(wvC1);   // c1K winner coords
        const bool cWin = (c1K < Mkey);
        const u64 win = cWin ? c1K : Mkey;
        bd2 = hi32f(win);
        bx = cWin ? cx : mx;
        by = cWin ? cy : my;
        // pre-steer (verified math)
        const float dirx = sub_rn(sx, bx), diry = sub_rn(sy, by);
        const float dist = __fsqrt_rn(add_rn(bd2, 1e-12f));
        const float scl = (dist > 5.0f) ? __fdiv_rn(5.0f, dist) : 1.0f;
        nx = add_rn(bx, mul_rn(dirx, scl));
        ny = add_rn(by, mul_rn(diry, scl));
        sh.c.qtmp[lane] = packf2(nx, ny);   // pre-pop q
        sh.c.bd2[lane] = bd2;               // post-merge bd2
      }
      __syncthreads();                      // B1: (q, bd2) shared

      // ---- Phase B (all waves): scan t-range [TPW*w, TPW*w+TPW) ----
      // Exactness as r9: bits computed from pre-pop q and post-merge bd2;
      // pops recheck exactly and re-add changed steps.
      {
        float qxl, qyl, bb;
        if (wave == 0) { qxl = nx; qyl = ny; bb = bd2; }
        else {
          const u64 qv = sh.c.qtmp[lane];
          qxl = lo32f(qv); qyl = hi32f(qv);
          bb = sh.c.bd2[lane];
        }
        unsigned mw = 0;
        const int t0 = wave * TPW;
        #pragma unroll
        for (int tt = 0; tt < TPW; ++tt) {
          const int t = t0 + tt;
          const float px = bcastf(qxl, t);
          const float py = bcastf(qyl, t);
          const float d = dist2_rn(px, py, sx, sy);
          const u64 bal = __ballot(d < bb);
          if (t < 63 && (bal >> (t + 1)) != 0ull) mw |= (1u << tt);
        }
        sh.c.mask[wave] = ((u64)mw) << (wave * TPW);
      }
      __syncthreads();                      // B2: masks ready

      // ---- Phase C (wave 0): pops (r9-exact) + publish ----
      if (wave == 0) {
        u64 cand = 0;
        #pragma unroll
        for (int w = 0; w < NWAVES; ++w) cand |= sh.c.mask[w];
        // speculative ring load for merge j+1 (slot (j-2)&3): issue BEFORE
        // pops for maximal flight time; decoded in phase E.
        if (j >= 2 && j + 1 < NCHUNKS)
          kvPre = ld_agent(&MbufK[(((unsigned)(j - 2)) & 3u) * 64 + lane]);
        while (cand) {
          const int t = (int)__builtin_ctzll(cand);
          cand &= (cand - 1);
          const float px = bcastf(nx, t);
          const float py = bcastf(ny, t);
          const float d = dist2_rn(px, py, sx, sy);
          const bool upd = (lane > t) && (d < bd2);
          const u64 ub = __ballot(upd);
          if (ub != 0ull) {
            if (upd) {                  // exact sequential update body
              bd2 = d;
              const float dirx = sub_rn(sx, px), diry = sub_rn(sy, py);
              const float dist = __fsqrt_rn(add_rn(d, 1e-12f));
              const float scl = (dist > 5.0f) ? __fdiv_rn(5.0f, dist) : 1.0f;
              nx = add_rn(px, mul_rn(dirx, scl));
              ny = add_rn(py, mul_rn(diry, scl));
            }
            cand |= ub;                 // changed steps become candidates
          }
        }
        const u64 pv = packf2(nx, ny);
        st_agent(&outU[c + lane + 1], pv);
        st_agent(&Nb[c + lane], pv);
        sh.c.qtmp[lane] = pv;           // FINAL q for the folds
      }
      __syncthreads();                      // B3: final q ready

      // ---- Phase D (all waves): fold t-range vs s_{j+1} and s_{j+2} ----
      {
        float qfx, qfy;
        if (wave == 0) { qfx = nx; qfy = ny; }
        else { const u64 qv = sh.c.qtmp[lane]; qfx = lo32f(qv); qfy = hi32f(qv); }
        u64 k1 = KEY_MAX, k2 = KEY_MAX;
        const int t0 = wave * TPW;
        #pragma unroll
        for (int tt = 0; tt < TPW; ++tt) {
          const int t = t0 + tt;
          const float px = bcastf(qfx, t);
          const float py = bcastf(qfy, t);
          const int idx = c + t + 1;
          const u64 kk1 = mkkey(dist2_rn(px, py, s1x, s1y), idx);
          if (kk1 < k1) k1 = kk1;
          const u64 kk2 = mkkey(dist2_rn(px, py, s2x, s2y), idx);
          if (kk2 < k2) k2 = kk2;
        }
        sh.c.fk1[wave][lane] = k1;
        sh.c.fk2[wave][lane] = k2;
      }
      __syncthreads();                      // B4: fold partials ready

      // ---- Phase E (wave 0): combine partials + pre-issue next gathers ----
      if (wave == 0) {
        u64 f1 = sh.c.fk1[0][lane];
        u64 f2 = sh.c.fk2[0][lane];
        #pragma unroll
        for (int w = 1; w < NWAVES; ++w) {
          const u64 x1 = sh.c.fk1[w][lane]; if (x1 < f1) f1 = x1;
          const u64 x2 = sh.c.fk2[w][lane]; if (x2 < f2) f2 = x2;
        }
        c1K = (c2K < f1) ? c2K : f1;    // key-min: exact, order-free ties
        c2K = f2;                       // (garbage s2 folds never consumed)
        // pre-issue winner-coord gathers for NEXT merge (hidden ~1 phase):
        const unsigned ic = (unsigned)(c1K & 0x1FFFu);
        wvC1 = ld_agent(&Nb[(ic ? ic : 1u) - 1u]);
        preOK = false;
        if (j >= 2 && j + 1 < NCHUNKS) {
          preOK = __all((int)(tagof(kvPre) == (unsigned)(j + 129)));
          if (preOK) {
            const unsigned im = (unsigned)kvPre & 0x1FFFu;
            wvM = ld_agent(&Nb[(im ? im : 1u) - 1u]);
          }
        }
      }

      // all waves: rotate samples
      sx = s1x; sy = s1y; s1x = s2x; s1y = s2y;
    }
  } else {
    // ================= scanners: blocks 1..64, one sample each =============
    // LAG-3: iter i (0..124): issue Nb load for chunk i; bulk-scan [1..64i]
    // from LDS + node 0 under it; wave-0 tail validates fresh chunk i via
    // the poison gate, folds one per lane, publishes tag i+131 into ring
    // slot i&3 (for merge j=i+3).
    const int b = blk - 1;

    for (int i = 0; i < NCHUNKS - 3; ++i) {
      const int c = i * NCHUNK;

      u64 nv = POISON64;
      if (wave == 0) nv = ld_agent(&Nb[c + lane]);   // issue early, check late

      // my sample: chunk i+3, slot b
      float sx, sy;
      load_sample(u, r, gx, gy, (i + 3) * NCHUNK + b, sx, sy);

      // ---- bulk scan of staged nodes [1..64i] + node 0 ----
      u64 key = KEY_MAX;
      if (tid == 0) key = mkkey(dist2_rn(n0x, n0y, sx, sy), 0);
      // 512 lanes stride node pairs; float4 = nodes (jj, jj+1), jj odd
      for (int jj = 1 + 2 * tid; jj < c; jj += 2 * NTHREADS) {
        const float4 p = *(const float4*)&sh.s.nodes[jj - 1];
        const u64 ka = mkkey(dist2_rn(p.x, p.y, sx, sy), jj);
        const u64 kb = mkkey(dist2_rn(p.z, p.w, sx, sy), jj + 1);
        if (ka < key) key = ka;     // lower idx first: exact argmin ties
        if (kb < key) key = kb;
      }
      #pragma unroll
      for (int m = 32; m >= 1; m >>= 1) {
        const u64 ok = __shfl_xor(key, m, 64);
        if (ok < key) key = ok;
      }
      if (lane == 0) sh.s.K[wave] = key;
      __syncthreads();                  // barrier A: partials ready

      // ---- wave-0 tail: validate fresh chunk i, stage, fold, publish ----
      if (wave == 0) {
        u64 kk = (lane < NWAVES) ? sh.s.K[lane] : KEY_MAX;
        u64 ok = __shfl_xor(kk, 1, 64); if (ok < kk) kk = ok;
        ok = __shfl_xor(kk, 2, 64);     if (ok < kk) kk = ok;
        ok = __shfl_xor(kk, 4, 64);     if (ok < kk) kk = ok;

        while (!__all((int)(nv != POISON64))) {   // data arrival = signal
          __builtin_amdgcn_s_sleep(1);
          nv = ld_agent(&Nb[c + lane]);
        }
        compiler_fence();
        const float px = lo32f(nv), py = hi32f(nv);
        {
          float2 p; p.x = px; p.y = py;
          sh.s.nodes[c + lane] = p;       // stage chunk i for future bulks
          const u64 ki = mkkey(dist2_rn(px, py, sx, sy), c + lane + 1);
          if (ki < kk) kk = ki;           // (d2,idx) key: order-free ties
        }
        #pragma unroll
        for (int m = 32; m >= 1; m >>= 1) {
          const u64 o2 = __shfl_xor(kk, m, 64);
          if (o2 < kk) kk = o2;
        }
        if (lane == 0) {
          u64* slot = MbufK + (((unsigned)i) & 3u) * 64;
          st_agent(&slot[b], kk | ((u64)(unsigned)(i + 131) << 13));
        }
      }
      // barrier B: gates next iter's bulk reads of freshly staged nodes and
      // K reuse.
      __syncthreads();
    }
  }
}

extern "C" void kernel_launch(void* const* d_in, const int* in_sizes, int n_in,
                              void* d_out, int out_size, void* d_ws, size_t ws_size,
                              hipStream_t stream) {
  const float* state = (const float*)d_in[0];
  const float* goal  = (const float*)d_in[1];
  const float* u     = (const float*)d_in[2];
  const float* r     = (const float*)d_in[3];
  float* out = (float*)d_out;
  unsigned* ws = (unsigned*)d_ws;
  (void)in_sizes; (void)n_in; (void)out_size; (void)ws_size;
  rrt_kernel<<<NSCAN + 1, NTHREADS, 0, stream>>>(state, goal, u, r, out, ws);
}